// Round 7
// baseline (54.571 us; speedup 1.0000x reference)
//
#include <hip/hip_runtime.h>

#define N 8192
#define LOG2E 1.4426950408889634f
#define LN2   0.6931471805599453f
#define NMOM  15   // Taylor terms n = 0..14

using f4 = __attribute__((ext_vector_type(4))) float;

#if __has_builtin(__builtin_amdgcn_exp2f)
#define EXP2(x) __builtin_amdgcn_exp2f(x)
#else
#define EXP2(x) exp2f(x)
#endif

// 128 blocks x 256 threads. Projects q,k,v -> aq,kp and emits per-block
// PARTIAL moments pm[j] = sum k^j, pt[j] = sum v*k^j over its 64 elements.
__global__ __launch_bounds__(256) void proj_kernel(
    const float* __restrict__ q, const float* __restrict__ k, const float* __restrict__ v,
    const float* __restrict__ Wq, const float* __restrict__ bq,
    const float* __restrict__ Wk, const float* __restrict__ bk,
    const float* __restrict__ Wv, const float* __restrict__ bv,
    float* __restrict__ aq, float* __restrict__ kp, float* __restrict__ pmom)
{
    const int tn = threadIdx.x & 63;
    const int tb = threadIdx.x >> 6;        // 0..3, splits the B=64 reduction
    const int n  = blockIdx.x * 64 + tn;
    float sq = 0.f, sk = 0.f, sv = 0.f;
#pragma unroll
    for (int bi = 0; bi < 16; ++bi) {
        const int b = tb * 16 + bi;
        sq = fmaf(q[b * N + n], Wq[b], sq);
        sk = fmaf(k[b * N + n], Wk[b], sk);
        sv = fmaf(v[b * N + n], Wv[b], sv);
    }
    __shared__ float red[3][4][64];
    red[0][tb][tn] = sq; red[1][tb][tn] = sk; red[2][tb][tn] = sv;
    __syncthreads();
    if (tb == 0) {
        const float fq = red[0][0][tn] + red[0][1][tn] + red[0][2][tn] + red[0][3][tn];
        const float fk = red[1][0][tn] + red[1][1][tn] + red[1][2][tn] + red[1][3][tn];
        const float fv = red[2][0][tn] + red[2][1][tn] + red[2][2][tn] + red[2][3][tn];
        aq[n] = (fq + bq[0]) * 0.125f * LOG2E;   // fold 1/sqrt(dk) and log2e
        const float kq = fk + bk[0];
        const float vq = fv + bv[0];
        kp[n] = kq;

        float pm[NMOM], pt[NMOM];
        float p = 1.f;
#pragma unroll
        for (int j = 0; j < NMOM; ++j) { pm[j] = p; pt[j] = vq * p; p *= kq; }
#pragma unroll
        for (int off = 32; off; off >>= 1) {
#pragma unroll
            for (int j = 0; j < NMOM; ++j) {
                pm[j] += __shfl_xor(pm[j], off);
                pt[j] += __shfl_xor(pt[j], off);
            }
        }
        if (tn == 0) {
            float* pb = pmom + blockIdx.x * 32;
#pragma unroll
            for (int j = 0; j < NMOM; ++j) { pb[j] = pm[j]; pb[16 + j] = pt[j]; }
            pb[15] = 0.f; pb[31] = 0.f;      // keep unused slots clean
        }
    }
}

// 16 blocks x 512 threads. Reduce the 128 partial-moment vectors -> global
// moments (invf-scaled), then per row r (one thread each): Horner in
// b = a_r*ln2 gives s_r (denominator) and t_r (numerator);
// out[r] = t/s ; cc[r] = -log2(s).
__global__ __launch_bounds__(512) void const_kernel(
    const float* __restrict__ aq, const float* __restrict__ pmom,
    float* __restrict__ out, float* __restrict__ cc)
{
    __shared__ float psum[32][16];
    __shared__ float M[32];
    const int tid = threadIdx.x;
    {
        const int j = tid >> 4;              // moment slot 0..31
        const int c = tid & 15;              // chunk 0..15
        float s = 0.f;
#pragma unroll
        for (int i = 0; i < 8; ++i) s += pmom[(c * 8 + i) * 32 + j];
        psum[j][c] = s;
    }
    __syncthreads();
    if (tid < 32) {
        static const float invf16[16] = {
            1.0f, 1.0f, 0.5f, 1.6666666666666666e-01f, 4.1666666666666664e-02f,
            8.3333333333333332e-03f, 1.3888888888888889e-03f, 1.9841269841269841e-04f,
            2.4801587301587302e-05f, 2.7557319223985893e-06f, 2.7557319223985888e-07f,
            2.5052108385441720e-08f, 2.0876756987868100e-09f, 1.6059043836821613e-10f,
            1.1470745597729725e-11f, 0.0f };
        float s = 0.f;
#pragma unroll
        for (int c = 0; c < 16; ++c) s += psum[tid][c];
        M[tid] = s * invf16[tid & 15];
    }
    __syncthreads();
    const int r = blockIdx.x * 512 + tid;
    const float a2 = aq[r];                  // log2-domain coefficient
    const float b  = a2 * LN2;               // natural-domain coefficient
    float s = M[NMOM - 1], t = M[16 + NMOM - 1];
#pragma unroll
    for (int nn = NMOM - 2; nn >= 0; --nn) {
        s = fmaf(s, b, M[nn]);
        t = fmaf(t, b, M[16 + nn]);
    }
    out[r] = t / s;
    cc[r] = -__log2f(s);
}

// Pure store stream, NO LDS, NO barriers. 1024 blocks x 256 threads,
// 2 rows/wave sharing each kp read (kp is 32 KB -> L1/L2 resident).
// Per iteration: 1 coalesced 16B load + 8 fma + 8 exp2 + 2 coalesced stores.
__global__ __launch_bounds__(256) void attn_kernel(
    const float* __restrict__ kp, const float* __restrict__ aq,
    const float* __restrict__ cc, float* __restrict__ attn)
{
    const int tid = threadIdx.x, lane = tid & 63, wave = tid >> 6;
    const int r0 = blockIdx.x * 8 + wave * 2;
    const float a0 = aq[r0],     c0 = cc[r0];
    const float a1 = aq[r0 + 1], c1 = cc[r0 + 1];
    const f4* __restrict__ kp4 = reinterpret_cast<const f4*>(kp);
    f4* __restrict__ arow0 = reinterpret_cast<f4*>(attn + (size_t)r0 * N);
    f4* __restrict__ arow1 = reinterpret_cast<f4*>(attn + (size_t)(r0 + 1) * N);
#pragma unroll 8
    for (int it = 0; it < 32; ++it) {
        const f4 kk = kp4[lane + it * 64];
        f4 w0, w1;
        w0[0] = EXP2(fmaf(a0, kk[0], c0));
        w0[1] = EXP2(fmaf(a0, kk[1], c0));
        w0[2] = EXP2(fmaf(a0, kk[2], c0));
        w0[3] = EXP2(fmaf(a0, kk[3], c0));
        w1[0] = EXP2(fmaf(a1, kk[0], c1));
        w1[1] = EXP2(fmaf(a1, kk[1], c1));
        w1[2] = EXP2(fmaf(a1, kk[2], c1));
        w1[3] = EXP2(fmaf(a1, kk[3], c1));
        arow0[lane + it * 64] = w0;
        arow1[lane + it * 64] = w1;
    }
}

extern "C" void kernel_launch(void* const* d_in, const int* in_sizes, int n_in,
                              void* d_out, int out_size, void* d_ws, size_t ws_size,
                              hipStream_t stream)
{
    const float* q  = (const float*)d_in[0];
    const float* k  = (const float*)d_in[1];
    const float* v  = (const float*)d_in[2];
    const float* Wq = (const float*)d_in[3];
    const float* bq = (const float*)d_in[4];
    const float* Wk = (const float*)d_in[5];
    const float* bk = (const float*)d_in[6];
    const float* Wv = (const float*)d_in[7];
    const float* bv = (const float*)d_in[8];

    float* out  = (float*)d_out;       // [N]  (first output)
    float* attn = out + N;             // [N,N] (second output)

    float* kp   = (float*)d_ws;        // projected k
    float* aq   = kp + N;              // qp * (1/8) * log2e
    float* cc   = aq + N;              // per-row -log2(sum)
    float* pmom = cc + N;              // [128][32] partial moments

    proj_kernel<<<128, 256, 0, stream>>>(q, k, v, Wq, bq, Wk, bk, Wv, bv, aq, kp, pmom);
    const_kernel<<<16, 512, 0, stream>>>(aq, pmom, out, cc);
    attn_kernel<<<1024, 256, 0, stream>>>(kp, aq, cc, attn);
}